// Round 1
// baseline (266.933 us; speedup 1.0000x reference)
//
#include <hip/hip_runtime.h>
#include <hip/hip_bf16.h>
#include <stdint.h>

#define B_N 8192
#define D_K 512
#define TEMP_INV 10.0f   // 1/TEMPERATURE
#define HNW 1.5f         // 1 + HARD_NEG_WEIGHT

typedef short bf16x8 __attribute__((ext_vector_type(8)));
typedef float f32x4 __attribute__((ext_vector_type(4)));

// order-preserving float<->uint key for atomicMax on floats
__device__ __forceinline__ unsigned fkey(float f) {
  unsigned u = __float_as_uint(f);
  return (u & 0x80000000u) ? ~u : (u | 0x80000000u);
}
__device__ __forceinline__ float unkey(unsigned k) {
  unsigned u = (k & 0x80000000u) ? (k & 0x7FFFFFFFu) : ~k;
  return __uint_as_float(u);
}
__device__ __forceinline__ unsigned short f2bf(float f) {
  unsigned u = __float_as_uint(f);
  u += 0x7FFFu + ((u >> 16) & 1u);   // round-to-nearest-even
  return (unsigned short)(u >> 16);
}

__global__ void cvt_kernel(const float* __restrict__ in, unsigned short* __restrict__ out) {
  int i = (blockIdx.x * 256 + threadIdx.x) * 4;
  float4 f = *reinterpret_cast<const float4*>(in + i);
  ushort4 o;
  o.x = f2bf(f.x); o.y = f2bf(f.y); o.z = f2bf(f.z); o.w = f2bf(f.w);
  *reinterpret_cast<ushort4*>(out + i) = o;
}

#define GLOAD16(gsrc, ldst)                                                       \
  __builtin_amdgcn_global_load_lds(                                               \
      (const __attribute__((address_space(1))) void*)(gsrc),                      \
      (__attribute__((address_space(3))) void*)(ldst), 16, 0, 0)

// PHASE 1: row max/argmax (excl diag) + col raw max + diag
// PHASE 2: row/col exp-sums of hard_logits
template <int PHASE>
__launch_bounds__(256, 2)
__global__ void gemm_phase(const unsigned short* __restrict__ Ibf,
                           const unsigned short* __restrict__ Sbf,
                           unsigned long long* __restrict__ rowPack,
                           unsigned* __restrict__ colKey,
                           float* __restrict__ diag,
                           const float* __restrict__ Mrow,
                           const int* __restrict__ hardest,
                           float* __restrict__ rowsum,
                           float* __restrict__ colsum) {
  __shared__ unsigned short As[128 * 32];  // [row][k] row-major, 8 KB
  __shared__ unsigned short Bs[128 * 32];

  const int tid = threadIdx.x;
  const int lane = tid & 63;
  const int wv = tid >> 6;
  const int rb0 = blockIdx.x * 128;
  const int cb0 = blockIdx.y * 128;
  const int wrl = (wv >> 1) * 64;          // wave row offset in tile
  const int wcl = (wv & 1) * 64;           // wave col offset in tile
  const int l15 = lane & 15;
  const int g4 = lane >> 4;

  // staging: thread t covers 16B chunk t of each 4 KB half-tile
  const int srow = tid >> 2;               // 0..63
  const int scol = (tid & 3) * 8;          // bf16 elems
  const unsigned short* aS0 = Ibf + (rb0 + srow) * D_K + scol;
  const unsigned short* aS1 = aS0 + 64 * D_K;
  const unsigned short* bS0 = Sbf + (cb0 + srow) * D_K + scol;
  const unsigned short* bS1 = bS0 + 64 * D_K;
  char* aD = (char*)As + wv * 1024;        // wave-uniform LDS dest base
  char* bD = (char*)Bs + wv * 1024;

  f32x4 acc[4][4] = {};

  for (int k0 = 0; k0 < D_K; k0 += 32) {
    GLOAD16(aS0 + k0, aD);
    GLOAD16(aS1 + k0, aD + 4096);
    GLOAD16(bS0 + k0, bD);
    GLOAD16(bS1 + k0, bD + 4096);
    __syncthreads();
    bf16x8 af[4], bfg[4];
#pragma unroll
    for (int mi = 0; mi < 4; ++mi)
      af[mi] = *reinterpret_cast<const bf16x8*>(&As[(wrl + mi * 16 + l15) * 32 + g4 * 8]);
#pragma unroll
    for (int ni = 0; ni < 4; ++ni)
      bfg[ni] = *reinterpret_cast<const bf16x8*>(&Bs[(wcl + ni * 16 + l15) * 32 + g4 * 8]);
#pragma unroll
    for (int mi = 0; mi < 4; ++mi)
#pragma unroll
      for (int ni = 0; ni < 4; ++ni)
        acc[mi][ni] = __builtin_amdgcn_mfma_f32_16x16x32_bf16(af[mi], bfg[ni], acc[mi][ni], 0, 0, 0);
    __syncthreads();
  }

  const int rb = rb0 + wrl;  // wave's global row base
  const int cb = cb0 + wcl;  // wave's global col base

  if (PHASE == 1) {
    // --- per-row max/argmax excluding diagonal ---
#pragma unroll
    for (int mi = 0; mi < 4; ++mi) {
#pragma unroll
      for (int v = 0; v < 4; ++v) {
        int grow = rb + mi * 16 + g4 * 4 + v;
        float best = -3.4e38f;
        int bcol = 0;
#pragma unroll
        for (int ni = 0; ni < 4; ++ni) {
          float val = acc[mi][ni][v] * TEMP_INV;
          int gcol = cb + ni * 16 + l15;
          if (gcol == grow) {
            diag[grow] = val;
          } else if (val > best) {
            best = val;
            bcol = gcol;
          }
        }
        // reduce over the 16-lane group (these lanes share the same row)
        for (int off = 1; off < 16; off <<= 1) {
          float ov = __shfl_xor(best, off);
          int oc = __shfl_xor(bcol, off);
          if (ov > best || (ov == best && oc < bcol)) { best = ov; bcol = oc; }
        }
        if (l15 == 0) {
          unsigned long long pk =
              ((unsigned long long)fkey(best) << 32) | (unsigned)(8191 - bcol);
          atomicMax(&rowPack[grow], pk);
        }
      }
    }
    // --- per-column raw max ---
#pragma unroll
    for (int ni = 0; ni < 4; ++ni) {
      float best = -3.4e38f;
#pragma unroll
      for (int mi = 0; mi < 4; ++mi)
#pragma unroll
        for (int v = 0; v < 4; ++v)
          best = fmaxf(best, acc[mi][ni][v] * TEMP_INV);
      best = fmaxf(best, __shfl_xor(best, 16));
      best = fmaxf(best, __shfl_xor(best, 32));
      if (g4 == 0) atomicMax(&colKey[cb + ni * 16 + l15], fkey(best));
    }
  } else {
    // --- PHASE 2: exp-sums ---
    float cs[4] = {0.f, 0.f, 0.f, 0.f};
    float Nc[4];
#pragma unroll
    for (int ni = 0; ni < 4; ++ni) Nc[ni] = unkey(colKey[cb + ni * 16 + l15]);
#pragma unroll
    for (int mi = 0; mi < 4; ++mi) {
#pragma unroll
      for (int v = 0; v < 4; ++v) {
        int grow = rb + mi * 16 + g4 * 4 + v;
        float M = Mrow[grow];
        int hd = hardest[grow];
        float rs = 0.f;
#pragma unroll
        for (int ni = 0; ni < 4; ++ni) {
          int gcol = cb + ni * 16 + l15;
          float val = acc[mi][ni][v] * TEMP_INV;
          float hl = (gcol == hd) ? HNW * val : val;
          rs += __expf(hl - M);
          cs[ni] += __expf(hl - Nc[ni]);
        }
        for (int off = 1; off < 16; off <<= 1) rs += __shfl_xor(rs, off);
        if (l15 == 0) atomicAdd(&rowsum[grow], rs);
      }
    }
#pragma unroll
    for (int ni = 0; ni < 4; ++ni) {
      cs[ni] += __shfl_xor(cs[ni], 16);
      cs[ni] += __shfl_xor(cs[ni], 32);
      if (g4 == 0) atomicAdd(&colsum[cb + ni * 16 + l15], cs[ni]);
    }
  }
}

__global__ void mid_kernel(const unsigned long long* __restrict__ rowPack,
                           const float* __restrict__ diag,
                           float* __restrict__ Mrow,
                           int* __restrict__ hardest,
                           unsigned* __restrict__ colKey) {
  int i = blockIdx.x * 256 + threadIdx.x;
  unsigned long long pk = rowPack[i];
  float h = unkey((unsigned)(pk >> 32));
  int idx = 8191 - (int)(pk & 0xFFFFFFFFu);
  hardest[i] = idx;
  float hs = HNW * h;
  Mrow[i] = fmaxf(fmaxf(h, hs), diag[i]);
  atomicMax(&colKey[idx], fkey(hs));  // column max of hard_logits
}

__global__ void finalize_kernel(const float* __restrict__ Mrow,
                                const float* __restrict__ rowsum,
                                const unsigned* __restrict__ colKey,
                                const float* __restrict__ colsum,
                                const float* __restrict__ diag,
                                float* __restrict__ out) {
  __shared__ double red[256];
  double acc = 0.0;
  for (int i = threadIdx.x; i < B_N; i += 256) {
    float rowLSE = Mrow[i] + logf(rowsum[i]);
    float colLSE = unkey(colKey[i]) + logf(colsum[i]);
    acc += 0.5 * ((double)rowLSE + (double)colLSE) - (double)diag[i];
  }
  red[threadIdx.x] = acc;
  __syncthreads();
  for (int s = 128; s > 0; s >>= 1) {
    if (threadIdx.x < s) red[threadIdx.x] += red[threadIdx.x + s];
    __syncthreads();
  }
  if (threadIdx.x == 0) out[0] = (float)(red[0] / (double)B_N);
}

extern "C" void kernel_launch(void* const* d_in, const int* in_sizes, int n_in,
                              void* d_out, int out_size, void* d_ws, size_t ws_size,
                              hipStream_t stream) {
  const float* img = (const float*)d_in[0];
  const float* sng = (const float*)d_in[1];
  char* ws = (char*)d_ws;

  // workspace layout (bytes)
  unsigned short* Ibf = (unsigned short*)(ws);                       // 8 MB
  unsigned short* Sbf = (unsigned short*)(ws + 8388608);             // 8 MB
  unsigned long long* rowPack = (unsigned long long*)(ws + 16777216);// 64 KB (zeroed)
  unsigned* colKey = (unsigned*)(ws + 16842752);                     // 32 KB (zeroed)
  float* rowsum = (float*)(ws + 16875520);                           // 32 KB (zeroed)
  float* colsum = (float*)(ws + 16908288);                           // 32 KB (zeroed)
  float* diag = (float*)(ws + 16941056);                             // 32 KB
  float* Mrow = (float*)(ws + 16973824);                             // 32 KB
  int* hardest = (int*)(ws + 17006592);                              // 32 KB
  if (ws_size < 17039360) return;

  hipMemsetAsync(ws + 16777216, 0, 163840, stream);
  cvt_kernel<<<4096, 256, 0, stream>>>(img, Ibf);
  cvt_kernel<<<4096, 256, 0, stream>>>(sng, Sbf);
  dim3 g(64, 64);
  gemm_phase<1><<<g, 256, 0, stream>>>(Ibf, Sbf, rowPack, colKey, diag, Mrow, hardest, rowsum, colsum);
  mid_kernel<<<32, 256, 0, stream>>>(rowPack, diag, Mrow, hardest, colKey);
  gemm_phase<2><<<g, 256, 0, stream>>>(Ibf, Sbf, rowPack, colKey, diag, Mrow, hardest, rowsum, colsum);
  finalize_kernel<<<1, 256, 0, stream>>>(Mrow, rowsum, colKey, colsum, diag, (float*)d_out);
}

// Round 2
// 263.776 us; speedup vs baseline: 1.0120x; 1.0120x over previous
//
#include <hip/hip_runtime.h>
#include <hip/hip_bf16.h>
#include <stdint.h>

#define B_N 8192
#define D_K 512
#define TEMP_INV 10.0f   // 1/TEMPERATURE
#define HNW 1.5f         // 1 + HARD_NEG_WEIGHT

typedef short bf16x8 __attribute__((ext_vector_type(8)));
typedef float f32x4 __attribute__((ext_vector_type(4)));

// order-preserving float<->uint key for atomicMax on floats
__device__ __forceinline__ unsigned fkey(float f) {
  unsigned u = __float_as_uint(f);
  return (u & 0x80000000u) ? ~u : (u | 0x80000000u);
}
__device__ __forceinline__ float unkey(unsigned k) {
  unsigned u = (k & 0x80000000u) ? (k & 0x7FFFFFFFu) : ~k;
  return __uint_as_float(u);
}
__device__ __forceinline__ unsigned short f2bf(float f) {
  unsigned u = __float_as_uint(f);
  u += 0x7FFFu + ((u >> 16) & 1u);   // round-to-nearest-even
  return (unsigned short)(u >> 16);
}

__global__ void cvt_kernel(const float* __restrict__ in, unsigned short* __restrict__ out) {
  int i = (blockIdx.x * 256 + threadIdx.x) * 4;
  float4 f = *reinterpret_cast<const float4*>(in + i);
  ushort4 o;
  o.x = f2bf(f.x); o.y = f2bf(f.y); o.z = f2bf(f.z); o.w = f2bf(f.w);
  *reinterpret_cast<ushort4*>(out + i) = o;
}

#define GLOAD16(gsrc, ldst)                                                       \
  __builtin_amdgcn_global_load_lds(                                               \
      (const __attribute__((address_space(1))) void*)(gsrc),                      \
      (__attribute__((address_space(3))) void*)(ldst), 16, 0, 0)

// PHASE 1: row max/argmax (excl diag) + col raw max + diag
// PHASE 2: row/col exp-sums of hard_logits
template <int PHASE>
__launch_bounds__(256, 2)
__global__ void gemm_phase(const unsigned short* __restrict__ Ibf,
                           const unsigned short* __restrict__ Sbf,
                           unsigned long long* __restrict__ rowPack,
                           unsigned* __restrict__ colKey,
                           float* __restrict__ diag,
                           const float* __restrict__ Mrow,
                           const int* __restrict__ hardest,
                           float* __restrict__ rowsum,
                           float* __restrict__ colsum) {
  __shared__ unsigned short As[128 * 32];  // [row][k] row-major, 8 KB, chunk-swizzled
  __shared__ unsigned short Bs[128 * 32];

  const int tid = threadIdx.x;
  const int lane = tid & 63;
  const int wv = tid >> 6;
  const int rb0 = blockIdx.x * 128;
  const int cb0 = blockIdx.y * 128;
  const int wrl = (wv >> 1) * 64;          // wave row offset in tile
  const int wcl = (wv & 1) * 64;           // wave col offset in tile
  const int l15 = lane & 15;
  const int g4 = lane >> 4;

  // staging: thread t covers 16B chunk t of each 4 KB half-tile.
  // LDS dest is linear (global_load_lds), so the bank-swizzle is applied by
  // permuting the GLOBAL source chunk: slot (row, c) holds global chunk
  // c ^ ((row>>1)&3)  (involution; read side applies the same XOR).
  const int srow = tid >> 2;               // 0..63
  const int schunk = (tid & 3) ^ ((srow >> 1) & 3);
  const int scol = schunk * 8;             // bf16 elems
  const unsigned short* aS0 = Ibf + (rb0 + srow) * D_K + scol;
  const unsigned short* aS1 = aS0 + 64 * D_K;
  const unsigned short* bS0 = Sbf + (cb0 + srow) * D_K + scol;
  const unsigned short* bS1 = bS0 + 64 * D_K;
  char* aD = (char*)As + wv * 1024;        // wave-uniform LDS dest base
  char* bD = (char*)Bs + wv * 1024;

  // fragment read: row = base + l15 (base multiple of 16), so
  // (row>>1)&3 == (l15>>1)&3 — per-lane constant chunk swizzle.
  const int kchunk8 = (g4 ^ ((l15 >> 1) & 3)) * 8;

  f32x4 acc[4][4] = {};

  for (int k0 = 0; k0 < D_K; k0 += 32) {
    GLOAD16(aS0 + k0, aD);
    GLOAD16(aS1 + k0, aD + 4096);
    GLOAD16(bS0 + k0, bD);
    GLOAD16(bS1 + k0, bD + 4096);
    __syncthreads();
    bf16x8 af[4], bfg[4];
#pragma unroll
    for (int mi = 0; mi < 4; ++mi)
      af[mi] = *reinterpret_cast<const bf16x8*>(&As[(wrl + mi * 16 + l15) * 32 + kchunk8]);
#pragma unroll
    for (int ni = 0; ni < 4; ++ni)
      bfg[ni] = *reinterpret_cast<const bf16x8*>(&Bs[(wcl + ni * 16 + l15) * 32 + kchunk8]);
#pragma unroll
    for (int mi = 0; mi < 4; ++mi)
#pragma unroll
      for (int ni = 0; ni < 4; ++ni)
        acc[mi][ni] = __builtin_amdgcn_mfma_f32_16x16x32_bf16(af[mi], bfg[ni], acc[mi][ni], 0, 0, 0);
    __syncthreads();
  }

  const int rb = rb0 + wrl;  // wave's global row base
  const int cb = cb0 + wcl;  // wave's global col base

  if (PHASE == 1) {
    // --- per-row max/argmax excluding diagonal ---
#pragma unroll
    for (int mi = 0; mi < 4; ++mi) {
#pragma unroll
      for (int v = 0; v < 4; ++v) {
        int grow = rb + mi * 16 + g4 * 4 + v;
        float best = -3.4e38f;
        int bcol = 0;
#pragma unroll
        for (int ni = 0; ni < 4; ++ni) {
          float val = acc[mi][ni][v] * TEMP_INV;
          int gcol = cb + ni * 16 + l15;
          if (gcol == grow) {
            diag[grow] = val;
          } else if (val > best) {
            best = val;
            bcol = gcol;
          }
        }
        // reduce over the 16-lane group (these lanes share the same row)
        for (int off = 1; off < 16; off <<= 1) {
          float ov = __shfl_xor(best, off);
          int oc = __shfl_xor(bcol, off);
          if (ov > best || (ov == best && oc < bcol)) { best = ov; bcol = oc; }
        }
        if (l15 == 0) {
          unsigned long long pk =
              ((unsigned long long)fkey(best) << 32) | (unsigned)(8191 - bcol);
          atomicMax(&rowPack[grow], pk);
        }
      }
    }
    // --- per-column raw max ---
#pragma unroll
    for (int ni = 0; ni < 4; ++ni) {
      float best = -3.4e38f;
#pragma unroll
      for (int mi = 0; mi < 4; ++mi)
#pragma unroll
        for (int v = 0; v < 4; ++v)
          best = fmaxf(best, acc[mi][ni][v] * TEMP_INV);
      best = fmaxf(best, __shfl_xor(best, 16));
      best = fmaxf(best, __shfl_xor(best, 32));
      if (g4 == 0) atomicMax(&colKey[cb + ni * 16 + l15], fkey(best));
    }
  } else {
    // --- PHASE 2: exp-sums ---
    float cs[4] = {0.f, 0.f, 0.f, 0.f};
    float Nc[4];
#pragma unroll
    for (int ni = 0; ni < 4; ++ni) Nc[ni] = unkey(colKey[cb + ni * 16 + l15]);
#pragma unroll
    for (int mi = 0; mi < 4; ++mi) {
#pragma unroll
      for (int v = 0; v < 4; ++v) {
        int grow = rb + mi * 16 + g4 * 4 + v;
        float M = Mrow[grow];
        int hd = hardest[grow];
        float rs = 0.f;
#pragma unroll
        for (int ni = 0; ni < 4; ++ni) {
          int gcol = cb + ni * 16 + l15;
          float val = acc[mi][ni][v] * TEMP_INV;
          float hl = (gcol == hd) ? HNW * val : val;
          rs += __expf(hl - M);
          cs[ni] += __expf(hl - Nc[ni]);
        }
        for (int off = 1; off < 16; off <<= 1) rs += __shfl_xor(rs, off);
        if (l15 == 0) atomicAdd(&rowsum[grow], rs);
      }
    }
#pragma unroll
    for (int ni = 0; ni < 4; ++ni) {
      cs[ni] += __shfl_xor(cs[ni], 16);
      cs[ni] += __shfl_xor(cs[ni], 32);
      if (g4 == 0) atomicAdd(&colsum[cb + ni * 16 + l15], cs[ni]);
    }
  }
}

__global__ void mid_kernel(const unsigned long long* __restrict__ rowPack,
                           const float* __restrict__ diag,
                           float* __restrict__ Mrow,
                           int* __restrict__ hardest,
                           unsigned* __restrict__ colKey) {
  int i = blockIdx.x * 256 + threadIdx.x;
  unsigned long long pk = rowPack[i];
  float h = unkey((unsigned)(pk >> 32));
  int idx = 8191 - (int)(pk & 0xFFFFFFFFu);
  hardest[i] = idx;
  float hs = HNW * h;
  Mrow[i] = fmaxf(fmaxf(h, hs), diag[i]);
  atomicMax(&colKey[idx], fkey(hs));  // column max of hard_logits
}

__global__ void finalize_kernel(const float* __restrict__ Mrow,
                                const float* __restrict__ rowsum,
                                const unsigned* __restrict__ colKey,
                                const float* __restrict__ colsum,
                                const float* __restrict__ diag,
                                float* __restrict__ out) {
  __shared__ double red[256];
  double acc = 0.0;
  for (int i = threadIdx.x; i < B_N; i += 256) {
    float rowLSE = Mrow[i] + logf(rowsum[i]);
    float colLSE = unkey(colKey[i]) + logf(colsum[i]);
    acc += 0.5 * ((double)rowLSE + (double)colLSE) - (double)diag[i];
  }
  red[threadIdx.x] = acc;
  __syncthreads();
  for (int s = 128; s > 0; s >>= 1) {
    if (threadIdx.x < s) red[threadIdx.x] += red[threadIdx.x + s];
    __syncthreads();
  }
  if (threadIdx.x == 0) out[0] = (float)(red[0] / (double)B_N);
}

extern "C" void kernel_launch(void* const* d_in, const int* in_sizes, int n_in,
                              void* d_out, int out_size, void* d_ws, size_t ws_size,
                              hipStream_t stream) {
  const float* img = (const float*)d_in[0];
  const float* sng = (const float*)d_in[1];
  char* ws = (char*)d_ws;

  // workspace layout (bytes)
  unsigned short* Ibf = (unsigned short*)(ws);                       // 8 MB
  unsigned short* Sbf = (unsigned short*)(ws + 8388608);             // 8 MB
  unsigned long long* rowPack = (unsigned long long*)(ws + 16777216);// 64 KB (zeroed)
  unsigned* colKey = (unsigned*)(ws + 16842752);                     // 32 KB (zeroed)
  float* rowsum = (float*)(ws + 16875520);                           // 32 KB (zeroed)
  float* colsum = (float*)(ws + 16908288);                           // 32 KB (zeroed)
  float* diag = (float*)(ws + 16941056);                             // 32 KB
  float* Mrow = (float*)(ws + 16973824);                             // 32 KB
  int* hardest = (int*)(ws + 17006592);                              // 32 KB
  if (ws_size < 17039360) return;

  hipMemsetAsync(ws + 16777216, 0, 163840, stream);
  cvt_kernel<<<4096, 256, 0, stream>>>(img, Ibf);
  cvt_kernel<<<4096, 256, 0, stream>>>(sng, Sbf);
  dim3 g(64, 64);
  gemm_phase<1><<<g, 256, 0, stream>>>(Ibf, Sbf, rowPack, colKey, diag, Mrow, hardest, rowsum, colsum);
  mid_kernel<<<32, 256, 0, stream>>>(rowPack, diag, Mrow, hardest, colKey);
  gemm_phase<2><<<g, 256, 0, stream>>>(Ibf, Sbf, rowPack, colKey, diag, Mrow, hardest, rowsum, colsum);
  finalize_kernel<<<1, 256, 0, stream>>>(Mrow, rowsum, colKey, colsum, diag, (float*)d_out);
}